// Round 15
// baseline (80.887 us; speedup 1.0000x reference)
//
#include <hip/hip_runtime.h>
#include <hip/hip_bf16.h>

// Conv2dKan, fused MFMA kernel. b=16, cin=cout=64, H=W=32, K=3, PAD=1, BASIS=8.
// out[b,o,pix] = bias[o] + sum_{i,k,s8} Wt[i,k,o,s]*act(x[b,i,pix+off(k)])[s]
//   Wt[...,0]=w, Wt[...,s]=w*c[s] (s=1..7) bf16, layout [i][kpos][o][s]
//   act(x) = [silu(x), T1..T7(tanh x)] bf16; act(pad) = act(0) = [0,0,-1,0,1,0,-1,0]
//   bias[o] = sum_{i,k} w*c[...,0]  (T0==1)
// MFMA 16x16x32 bf16 (layouts HW-verified R3/R5): A/B: lane=(quad,l16), k=quad*8+s;
//   C/D: col=l16, row=quad*4+r.
// R15 (from pipe census: wf-L2 8.6us is the largest per-CU term; tiling invariant
//   wf/FLOP ~ 1/pix-per-wave): wave widened to 64 pix (2 rows) x 32 o x 16 ch ->
//   each wf feeds 4 MFMAs (wf-L2 halved to 4.3us). Block 256thr = 4 kq-waves,
//   grid (16b,16rp,2oh) = 512 blocks = 2/SIMD, 2 blocks/CU (LDS 69632B: dbuf
//   scratch [kq4][pos136][ch4]x16B; epilogue red overlays buf0). Single-exp act:
//   e=exp(x), sigmoid=e*rcp(1+e), tanh=1-2*rcp(e*e+1) (|x|<=5.5 -> no overflow).

#define CIN   64
#define COUT  64
#define HW    32
#define LL    1024
#define NS    8

typedef __attribute__((ext_vector_type(8))) short short8;
typedef __attribute__((ext_vector_type(4))) float f32x4;

// ws layout (bytes):
//   [0)       Wt    : 64*9*64*8 bf16 = 589824 B   ([i][kpos][o][s])
//   [589824)  bias  : 64 f32         = 256 B
//   [590080)  dummy : keep-alive sink for prefetch

__global__ void prep_kernel(const float* __restrict__ w,
                            const float* __restrict__ c,
                            __hip_bfloat16* __restrict__ Wt,
                            float* __restrict__ bias,
                            const float* __restrict__ x,
                            float* __restrict__ dummy) {
    const int bx = blockIdx.x;
    if (bx < 144) {
        // Wt part
        const int tid = bx * 256 + threadIdx.x;   // < 36864 = 64i*9k*64o
        const int i = tid / (9 * COUT);
        const int r = tid - i * 9 * COUT;
        const int k = r / COUT;
        const int o = r - k * COUT;
        const int widx = (i * COUT + o) * 9 + k;
        const float wv = w[widx];
        __hip_bfloat16* dst = Wt + (size_t)tid * NS;   // tid == (i*9+k)*64+o
        dst[0] = __float2bfloat16(wv);
#pragma unroll
        for (int s = 1; s < 8; ++s) dst[s] = __float2bfloat16(wv * c[widx * 8 + s]);
        return;
    }
    if (bx < 208) {
        // bias part: 64 blocks, one o each; 64-lane wave reduce over i.
        const int o = bx - 144;
        const int i = threadIdx.x;
        if (i >= 64) return;
        float v = 0.f;
#pragma unroll
        for (int k = 0; k < 9; ++k) {
            const int idx = (i * COUT + o) * 9 + k;
            v += w[idx] * c[idx * 8];
        }
#pragma unroll
        for (int off = 32; off > 0; off >>= 1) v += __shfl_down(v, off);
        if (i == 0) bias[o] = v;
        return;
    }
    // x-prefetch part: 1024 blocks, each touches one (b,ch) 4KB image -> L3 warm.
    const int idx = bx - 208;          // [0,1024)
    const int r  = idx & 7;
    const int m  = idx >> 3;
    const int b  = r + 8 * (m & 1);
    const int ch = m >> 1;
    const float4 v = ((const float4*)(x + (size_t)(b * CIN + ch) * LL))[threadIdx.x];
    const float acc = v.x + v.y + v.z + v.w;
    if (acc == 1.0e-37f) dummy[threadIdx.x] = acc;   // keep-alive; never taken in practice
}

// grid (16 b, 16 row-pairs, 2 oh), block 256 = 4 kq-waves.
// Wave: 2 rows x 32 pix (4 pixel-groups) x 32 o x 16 ch.
__global__ __launch_bounds__(256, 2) void kan_fused_kernel(
        const float* __restrict__ x,
        const __hip_bfloat16* __restrict__ Wt,
        const float* __restrict__ bias,
        float* __restrict__ out) {
    // double-buffered act scratch: 2 x [kq4][pos136][ch4] x 16B = 2 x 34816 B
    //   (pos = r4*34+col over 4 halo rows; [pos][ch] interleave -> conflict-free af)
    // epilogue overlay (buf0): float red[kq4][pix64][o 33pad] = 33792 B
    __shared__ __align__(16) unsigned short Wlds[34816];   // 69632 B

    const int tid   = threadIdx.x;
    const int kq    = tid >> 6;       // K-quarter: channels [kq*16, kq*16+16)
    const int lane  = tid & 63;
    const int quad  = lane >> 4;      // channel within 4-ch chunk
    const int l16   = lane & 15;

    const int b    = blockIdx.x;
    const int row0 = blockIdx.y * 2;
    const int oh   = blockIdx.z;      // o-half: [oh*32, oh*32+32)

    const unsigned short* WtU = (const unsigned short*)Wt;

    f32x4 acc[4][2];                  // [h: hr*2+hc][nt]
#pragma unroll
    for (int h = 0; h < 4; ++h)
#pragma unroll
        for (int nt = 0; nt < 2; ++nt) acc[h][nt] = (f32x4){0.f, 0.f, 0.f, 0.f};

    for (int chunk = 0; chunk < 4; ++chunk) {
        const int chbase = kq * 16 + chunk * 4;
        unsigned short* usd = Wlds + (chunk & 1) * 17408 + kq * 4352;  // 544 cells x 8

        // ---- act: 544 cells (4 rows x 34 cols x 4 ch), single-exp math ----
#pragma unroll
        for (int p = 0; p < 9; ++p) {
            const int cell = p * 64 + lane;
            if (cell < 544) {
                const int ch  = cell & 3;          // interleaved layout [pos][ch]
                const int pos = cell >> 2;         // 0..135
                const int r4  = (pos >= 102) ? 3 : ((pos >= 68) ? 2 : ((pos >= 34) ? 1 : 0));
                const int col = pos - r4 * 34;
                const int gy  = row0 - 1 + r4;
                const int gx  = col - 1;
                union { __hip_bfloat162 h2[4]; float4 f4; unsigned int u[4]; } U;
                if ((unsigned)gy < 32u && (unsigned)gx < 32u) {
                    const float xv = x[((size_t)(b * CIN + chbase + ch) * HW + gy) * HW + gx];
                    const float e   = __expf(xv);                       // one exp
                    const float sig = e * __builtin_amdgcn_rcpf(1.f + e);
                    const float res = xv * sig;                         // silu
                    const float t   = 1.f - 2.f * __builtin_amdgcn_rcpf(e * e + 1.f); // tanh
                    const float t2  = t + t;
                    const float T2 = __builtin_fmaf(t2, t,  -1.f);
                    const float T3 = __builtin_fmaf(t2, T2, -t);
                    const float T4 = __builtin_fmaf(t2, T3, -T2);
                    const float T5 = __builtin_fmaf(t2, T4, -T3);
                    const float T6 = __builtin_fmaf(t2, T5, -T4);
                    const float T7 = __builtin_fmaf(t2, T6, -T5);
                    U.h2[0] = __float22bfloat162_rn(make_float2(res, t));
                    U.h2[1] = __float22bfloat162_rn(make_float2(T2, T3));
                    U.h2[2] = __float22bfloat162_rn(make_float2(T4, T5));
                    U.h2[3] = __float22bfloat162_rn(make_float2(T6, T7));
                } else {
                    // act(0): pairs (0,0), (-1,0), (1,0), (-1,0)
                    U.u[0] = 0x00000000u; U.u[1] = 0x0000BF80u;
                    U.u[2] = 0x00003F80u; U.u[3] = 0x0000BF80u;
                }
                *(float4*)(usd + cell * 8) = U.f4;
            }
        }
        __syncthreads();   // scratch buf[chunk&1] ready (dbuf: next act hits other buf)

        // ---- MFMA: af from scratch, wf from global L2 (each wf feeds 4 MFMAs) ----
        const unsigned short* wchunk = WtU +
            ((size_t)(chbase + quad) * 9 * COUT + (oh << 5) + l16) * NS;
#pragma unroll
        for (int kpos = 0; kpos < 9; ++kpos) {
            const int dy = kpos / 3 - 1, dx = kpos % 3 - 1;
            short8 af[4];
#pragma unroll
            for (int hr = 0; hr < 2; ++hr) {
                const int posb = (1 + hr + dy) * 34 + (1 + dx);
                af[hr * 2 + 0] = *(const short8*)(usd + ((posb + l16) * 4 + quad) * 8);
                af[hr * 2 + 1] = *(const short8*)(usd + ((posb + 16 + l16) * 4 + quad) * 8);
            }
#pragma unroll
            for (int nt = 0; nt < 2; ++nt) {
                short8 wf = *(const short8*)(wchunk + (kpos * COUT + nt * 16) * NS);
#pragma unroll
                for (int h = 0; h < 4; ++h)
                    acc[h][nt] = __builtin_amdgcn_mfma_f32_16x16x32_bf16(wf, af[h], acc[h][nt], 0, 0, 0);
            }
        }
    }

    // ---- epilogue: reduce 4 K-quarters via padded LDS (overlays buf0; last MFMA
    //      chunk used buf1, and the chunk-3 barrier ordered all buf0 readers) ----
    float* red = (float*)Wlds;       // red[kq][pix64][33]
#pragma unroll
    for (int h = 0; h < 4; ++h)
#pragma unroll
        for (int nt = 0; nt < 2; ++nt)
#pragma unroll
            for (int r = 0; r < 4; ++r) {
                const int p  = (h >> 1) * 32 + (h & 1) * 16 + l16;
                const int ol = nt * 16 + quad * 4 + r;
                red[(kq * 64 + p) * 33 + ol] = acc[h][nt][r];
            }
    __syncthreads();

#pragma unroll
    for (int rep = 0; rep < 8; ++rep) {
        const int v  = rep * 256 + tid;   // 2048 = 64 pix x 32 o
        const int p  = v & 63;
        const int ol = v >> 6;
        const int o  = (oh << 5) + ol;
        const float s = red[p * 33 + ol] + red[(64 + p) * 33 + ol]
                      + red[(128 + p) * 33 + ol] + red[(192 + p) * 33 + ol] + bias[o];
        out[(size_t)(b * COUT + o) * LL + (row0 + (p >> 5)) * HW + (p & 31)] = s;
    }
}

extern "C" void kernel_launch(void* const* d_in, const int* in_sizes, int n_in,
                              void* d_out, int out_size, void* d_ws, size_t ws_size,
                              hipStream_t stream) {
    const float* x = (const float*)d_in[0];
    const float* w = (const float*)d_in[1];
    const float* c = (const float*)d_in[2];
    float* out = (float*)d_out;

    char* ws = (char*)d_ws;
    __hip_bfloat16* Wt    = (__hip_bfloat16*)(ws);
    float*          bias  = (float*)(ws + 589824);
    float*          dummy = (float*)(ws + 590080);

    // 144 Wt + 64 bias + 1024 x-prefetch = 1232 blocks, all parallel
    prep_kernel<<<1232, 256, 0, stream>>>(w, c, Wt, bias, x, dummy);
    kan_fused_kernel<<<dim3(16, 16, 2), 256, 0, stream>>>(x, Wt, bias, out);
}

// Round 16
// 77.257 us; speedup vs baseline: 1.0470x; 1.0470x over previous
//
#include <hip/hip_runtime.h>
#include <hip/hip_bf16.h>

// Conv2dKan, fused MFMA kernel. b=16, cin=cout=64, H=W=32, K=3, PAD=1, BASIS=8.
// out[b,o,pix] = bias[o] + sum_{i,k,s8} Wt[i,k,o,s]*act(x[b,i,pix+off(k)])[s]
//   Wt[...,0]=w, Wt[...,s]=w*c[s] (s=1..7) bf16, layout [i][kpos][o][s]
//   act(x) = [silu(x), T1..T7(tanh x)] bf16; act(pad) = act(0) = [0,0,-1,0,1,0,-1,0]
//   bias[o] = sum_{i,k} w*c[...,0]  (T0==1)
// MFMA 16x16x32 bf16 (layouts HW-verified R3/R5): A/B: lane=(quad,l16), k=quad*8+s;
//   C/D: col=l16, row=quad*4+r.
// R16 = R14 structure (best: 512thr = 8 waves kq4 x oh2, 4 waves/SIMD, oh-shared
//   act, conflict-free scratch) + :
//   1) x halo (64ch x 3rows x 34cols = 6528 f32, 26KB) preloaded into LDS once
//      per block with ~12 independent loads/thread (one max-MLP cold burst instead
//      of per-chunk miss chains after the harness's L2/L3-evicting ws fill).
//      Borders stored as 0.0 -> act path BRANCHLESS (act(0) computes exactly to
//      the padding vector; rcp(2) is exact).
//   2) single-exp act (R15-verified): e=exp(x), sig=e*rcp(1+e), tanh=1-2*rcp(e^2+1).
//   3) xlds layout [ch][pos102] (stride 102 = 6 mod 32 -> <=2-way = free).
//   LDS 78336B -> 2 blocks/CU. Epilogue red overlays x+buf0 only (not buf1).

#define CIN   64
#define COUT  64
#define HW    32
#define LL    1024
#define NS    8

typedef __attribute__((ext_vector_type(8))) short short8;
typedef __attribute__((ext_vector_type(4))) float f32x4;

// ws layout (bytes):
//   [0)       Wt    : 64*9*64*8 bf16 = 589824 B   ([i][kpos][o][s])
//   [589824)  bias  : 64 f32         = 256 B
//   [590080)  dummy : keep-alive sink for prefetch

__global__ void prep_kernel(const float* __restrict__ w,
                            const float* __restrict__ c,
                            __hip_bfloat16* __restrict__ Wt,
                            float* __restrict__ bias,
                            const float* __restrict__ x,
                            float* __restrict__ dummy) {
    const int bx = blockIdx.x;
    if (bx < 144) {
        // Wt part
        const int tid = bx * 256 + threadIdx.x;   // < 36864 = 64i*9k*64o
        const int i = tid / (9 * COUT);
        const int r = tid - i * 9 * COUT;
        const int k = r / COUT;
        const int o = r - k * COUT;
        const int widx = (i * COUT + o) * 9 + k;
        const float wv = w[widx];
        __hip_bfloat16* dst = Wt + (size_t)tid * NS;   // tid == (i*9+k)*64+o
        dst[0] = __float2bfloat16(wv);
#pragma unroll
        for (int s = 1; s < 8; ++s) dst[s] = __float2bfloat16(wv * c[widx * 8 + s]);
        return;
    }
    if (bx < 208) {
        // bias part: 64 blocks, one o each; 64-lane wave reduce over i.
        const int o = bx - 144;
        const int i = threadIdx.x;
        if (i >= 64) return;
        float v = 0.f;
#pragma unroll
        for (int k = 0; k < 9; ++k) {
            const int idx = (i * COUT + o) * 9 + k;
            v += w[idx] * c[idx * 8];
        }
#pragma unroll
        for (int off = 32; off > 0; off >>= 1) v += __shfl_down(v, off);
        if (i == 0) bias[o] = v;
        return;
    }
    // x-prefetch part: 1024 blocks, each touches one (b,ch) 4KB image -> L3 warm.
    const int idx = bx - 208;          // [0,1024)
    const int r  = idx & 7;
    const int m  = idx >> 3;
    const int b  = r + 8 * (m & 1);
    const int ch = m >> 1;
    const float4 v = ((const float4*)(x + (size_t)(b * CIN + ch) * LL))[threadIdx.x];
    const float acc = v.x + v.y + v.z + v.w;
    if (acc == 1.0e-37f) dummy[threadIdx.x] = acc;   // keep-alive; never taken in practice
}

// grid (16 b, 32 rows), block 512 = 8 waves = (kq4 x oh2). Wave: 32pix x 32o x 16ch.
__global__ __launch_bounds__(512, 4) void kan_fused_kernel(
        const float* __restrict__ x,
        const __hip_bfloat16* __restrict__ Wt,
        const float* __restrict__ bias,
        float* __restrict__ out) {
    // ushort units:
    //   [0,     13056): xlds  — float x[ch64][pos102] (zero-padded halo), 26112 B
    //   [13056, 26112): act scratch buf0 [kq4][pos102][ch4] x 16B
    //   [26112, 39168): act scratch buf1
    // epilogue overlay: float red[kq4][pix32][o 65pad] = 33280 B (xlds+buf0 only)
    __shared__ __align__(16) unsigned short Wlds[39168];   // 78336 B

    const int tid   = threadIdx.x;
    const int wv    = tid >> 6;
    const int lane  = tid & 63;
    const int quad  = lane >> 4;      // channel within 4-ch chunk
    const int l16   = lane & 15;
    const int kq    = wv >> 1;        // K-quarter: channels [kq*16, kq*16+16)
    const int oh    = wv & 1;         // o-half: [oh*32, oh*32+32)

    const int b   = blockIdx.x;
    const int row = blockIdx.y;

    const unsigned short* WtU = (const unsigned short*)Wt;
    float* xf = (float*)Wlds;         // xlds

    // ---- preload x halo: 6528 cells, 12.75/thread, one max-MLP burst ----
#pragma unroll
    for (int p = 0; p < 13; ++p) {
        const int cell = p * 512 + tid;
        if (cell < 6528) {
            const int ch  = cell / 102;
            const int pos = cell - ch * 102;
            const int r3  = (pos >= 68) ? 2 : ((pos >= 34) ? 1 : 0);
            const int col = pos - r3 * 34;
            const int gy  = row - 1 + r3;
            const int gx  = col - 1;
            float v = 0.f;   // border -> x=0 -> act computes exactly the pad vector
            if ((unsigned)gy < 32u && (unsigned)gx < 32u)
                v = x[((size_t)(b * CIN + ch) * HW + gy) * HW + gx];
            xf[ch * 102 + pos] = v;
        }
    }
    __syncthreads();

    f32x4 acc[2][2];                  // [h pixel-group][nt]
#pragma unroll
    for (int h = 0; h < 2; ++h)
#pragma unroll
        for (int nt = 0; nt < 2; ++nt) acc[h][nt] = (f32x4){0.f, 0.f, 0.f, 0.f};

    for (int chunk = 0; chunk < 4; ++chunk) {
        const int chbase = kq * 16 + chunk * 4;
        unsigned short* usd = Wlds + 13056 + (chunk & 1) * 13056 + kq * 3264;

        // ---- act: oh-pair splits 408 cells; BRANCHLESS, x from LDS, single exp ----
#pragma unroll
        for (int p = 0; p < 4; ++p) {
            const int cell = (p * 2 + oh) * 64 + lane;
            if (cell < 408) {
                const int ch  = cell & 3;          // interleaved layout [pos][ch]
                const int pos = cell >> 2;         // 0..101
                const float xv = xf[(chbase + ch) * 102 + pos];
                const float e   = __expf(xv);                         // one exp
                const float sig = e * __builtin_amdgcn_rcpf(1.f + e);
                const float res = xv * sig;                           // silu
                const float t   = 1.f - 2.f * __builtin_amdgcn_rcpf(__builtin_fmaf(e, e, 1.f)); // tanh
                const float t2  = t + t;
                const float T2 = __builtin_fmaf(t2, t,  -1.f);
                const float T3 = __builtin_fmaf(t2, T2, -t);
                const float T4 = __builtin_fmaf(t2, T3, -T2);
                const float T5 = __builtin_fmaf(t2, T4, -T3);
                const float T6 = __builtin_fmaf(t2, T5, -T4);
                const float T7 = __builtin_fmaf(t2, T6, -T5);
                union { __hip_bfloat162 h2[4]; float4 f4; } U;
                U.h2[0] = __float22bfloat162_rn(make_float2(res, t));
                U.h2[1] = __float22bfloat162_rn(make_float2(T2, T3));
                U.h2[2] = __float22bfloat162_rn(make_float2(T4, T5));
                U.h2[3] = __float22bfloat162_rn(make_float2(T6, T7));
                *(float4*)(usd + cell * 8) = U.f4;
            }
        }
        __syncthreads();   // scratch buf[chunk&1] ready; xlds reads done

        // ---- MFMA: af from shared scratch (contiguous lanes), wf from global L2 ----
        const unsigned short* wchunk = WtU +
            ((size_t)(chbase + quad) * 9 * COUT + (oh << 5) + l16) * NS;
#pragma unroll
        for (int kpos = 0; kpos < 9; ++kpos) {
            const int dy = kpos / 3 - 1, dx = kpos % 3 - 1;
            const int posb = (dy + 1) * 34 + (dx + 1);
            short8 af0 = *(const short8*)(usd + ((posb + l16) * 4 + quad) * 8);
            short8 af1 = *(const short8*)(usd + ((posb + 16 + l16) * 4 + quad) * 8);
#pragma unroll
            for (int nt = 0; nt < 2; ++nt) {
                short8 wf = *(const short8*)(wchunk + (kpos * COUT + nt * 16) * NS);
                acc[0][nt] = __builtin_amdgcn_mfma_f32_16x16x32_bf16(wf, af0, acc[0][nt], 0, 0, 0);
                acc[1][nt] = __builtin_amdgcn_mfma_f32_16x16x32_bf16(wf, af1, acc[1][nt], 0, 0, 0);
            }
        }
    }

    // ---- epilogue: reduce 4 K-quarters via padded LDS.
    //      red (33280B) overlays xlds+buf0 only; last MFMA chunk read buf1, and
    //      buf0/xlds readers were ordered by the chunk-3 act barrier. Each wave
    //      writes only its own acc -> no extra barrier needed before writes. ----
    float* red = (float*)Wlds;       // red[kq][pix32][65]
#pragma unroll
    for (int h = 0; h < 2; ++h)
#pragma unroll
        for (int nt = 0; nt < 2; ++nt)
#pragma unroll
            for (int r = 0; r < 4; ++r) {
                const int p = h * 16 + l16;
                const int o = (oh << 5) + nt * 16 + quad * 4 + r;
                red[(kq * 32 + p) * 65 + o] = acc[h][nt][r];
            }
    __syncthreads();

#pragma unroll
    for (int rep = 0; rep < 4; ++rep) {
        const int v = rep * 512 + tid;    // 2048 = 32 pix x 64 o
        const int p = v & 31;
        const int o = v >> 5;
        const float s = red[p * 65 + o] + red[(32 + p) * 65 + o]
                      + red[(64 + p) * 65 + o] + red[(96 + p) * 65 + o] + bias[o];
        out[(size_t)(b * COUT + o) * LL + row * HW + p] = s;
    }
}

extern "C" void kernel_launch(void* const* d_in, const int* in_sizes, int n_in,
                              void* d_out, int out_size, void* d_ws, size_t ws_size,
                              hipStream_t stream) {
    const float* x = (const float*)d_in[0];
    const float* w = (const float*)d_in[1];
    const float* c = (const float*)d_in[2];
    float* out = (float*)d_out;

    char* ws = (char*)d_ws;
    __hip_bfloat16* Wt    = (__hip_bfloat16*)(ws);
    float*          bias  = (float*)(ws + 589824);
    float*          dummy = (float*)(ws + 590080);

    // 144 Wt + 64 bias + 1024 x-prefetch = 1232 blocks, all parallel
    prep_kernel<<<1232, 256, 0, stream>>>(w, c, Wt, bias, x, dummy);
    kan_fused_kernel<<<dim3(16, 32), 512, 0, stream>>>(x, Wt, bias, out);
}